// Round 3
// baseline (1099.034 us; speedup 1.0000x reference)
//
#include <hip/hip_runtime.h>
#include <math.h>

#define NN 50000
#define EE 800000
#define FF 128

constexpr float LN_EPS = 1e-5f;
constexpr int NC = (NN + 255) / 256;   // 196 scan chunks

typedef float  f32x4  __attribute__((ext_vector_type(4)));
typedef short  s16x8  __attribute__((ext_vector_type(8)));

__device__ __forceinline__ float silu_f(float v) {
    return v / (1.f + __expf(-v));
}

__device__ __forceinline__ unsigned short f2bf(float f) {
    union { float f; unsigned u; } cv; cv.f = f;
    unsigned u = cv.u;
    u += 0x7fffu + ((u >> 16) & 1u);   // round-to-nearest-even
    return (unsigned short)(u >> 16);
}

// -------------------- prep: x -> bf16 --------------------
__global__ __launch_bounds__(256) void convert_x_kernel(
    const float* __restrict__ x, unsigned short* __restrict__ xb)
{
    int i = (blockIdx.x * 256 + threadIdx.x) * 8;
    float4 a = *(const float4*)&x[i];
    float4 b = *(const float4*)&x[i + 4];
    s16x8 o;
    o[0] = (short)f2bf(a.x); o[1] = (short)f2bf(a.y);
    o[2] = (short)f2bf(a.z); o[3] = (short)f2bf(a.w);
    o[4] = (short)f2bf(b.x); o[5] = (short)f2bf(b.y);
    o[6] = (short)f2bf(b.z); o[7] = (short)f2bf(b.w);
    *(s16x8*)&xb[i] = o;
}

// -------------------- prep: transpose weights -> bf16 --------------------
__global__ __launch_bounds__(256) void transpose_w_kernel(
    const float* __restrict__ ew1, const float* __restrict__ ew2,
    unsigned short* __restrict__ ew1T, unsigned short* __restrict__ ew2T)
{
    int o = blockIdx.x * 256 + threadIdx.x;
    if (o < 128 * 256) {
        int n = o >> 8, k = o & 255;
        ew1T[o] = f2bf(ew1[k * FF + n]);
    } else {
        int o2 = o - 128 * 256;
        int n = o2 >> 7, k = o2 & 127;
        ew2T[o2] = f2bf(ew2[k * FF + n]);
    }
}

// -------------------- counting sort by row --------------------
__global__ __launch_bounds__(256) void hist_kernel(
    const int* __restrict__ ei, int* __restrict__ cnt)
{
    int e = blockIdx.x * 256 + threadIdx.x;
    if (e < EE) atomicAdd(&cnt[ei[e]], 1);
}

__global__ __launch_bounds__(256) void chunk_sum_kernel(
    const int* __restrict__ cnt, int* __restrict__ chunkSum)
{
    __shared__ int s[256];
    int t = threadIdx.x;
    int idx = blockIdx.x * 256 + t;
    s[t] = (idx < NN) ? cnt[idx] : 0;
    __syncthreads();
    for (int off = 128; off > 0; off >>= 1) {
        if (t < off) s[t] += s[t + off];
        __syncthreads();
    }
    if (t == 0) chunkSum[blockIdx.x] = s[0];
}

__global__ __launch_bounds__(256) void scan_chunks_kernel(
    const int* __restrict__ chunkSum, int* __restrict__ chunkOff)
{
    __shared__ int s[256];
    int t = threadIdx.x;
    int v = (t < NC) ? chunkSum[t] : 0;
    s[t] = v;
    __syncthreads();
    for (int off = 1; off < 256; off <<= 1) {
        int u = (t >= off) ? s[t - off] : 0;
        __syncthreads();
        s[t] += u;
        __syncthreads();
    }
    if (t < NC) chunkOff[t] = s[t] - v;
}

__global__ __launch_bounds__(256) void scan_kernel(
    const int* __restrict__ cnt, const int* __restrict__ chunkOff,
    int* __restrict__ offs)
{
    __shared__ int s[256];
    int t = threadIdx.x;
    int idx = blockIdx.x * 256 + t;
    int v = (idx < NN) ? cnt[idx] : 0;
    s[t] = v;
    __syncthreads();
    for (int off = 1; off < 256; off <<= 1) {
        int u = (t >= off) ? s[t - off] : 0;
        __syncthreads();
        s[t] += u;
        __syncthreads();
    }
    if (idx < NN) offs[idx] = chunkOff[blockIdx.x] + s[t] - v;
}

__global__ __launch_bounds__(256) void scatter_idx_kernel(
    const int* __restrict__ ei, int* __restrict__ offs,
    int* __restrict__ sRow, int* __restrict__ sCol)
{
    int e = blockIdx.x * 256 + threadIdx.x;
    if (e < EE) {
        int r = ei[e], c = ei[EE + e];
        int p = atomicAdd(&offs[r], 1);
        sRow[p] = r;
        sCol[p] = c;
    }
}

// -------------------- edge kernel (MFMA bf16, sorted, segmented scatter) ----
constexpr int EPB  = 32;
constexpr int H1S  = 136;   // h1 LDS row stride (bf16 elems)
constexpr int ASTR = 132;   // aggL LDS row stride (f32 elems)

__global__ __launch_bounds__(256) void edge_kernel(
    const unsigned short* __restrict__ xb, const float* __restrict__ pos,
    const int* __restrict__ sRow, const int* __restrict__ sCol,
    const unsigned short* __restrict__ ew1T, const float* __restrict__ ew1,
    const float* __restrict__ eb1,
    const unsigned short* __restrict__ ew2T, const float* __restrict__ eb2,
    const float* __restrict__ cw,  const float* __restrict__ cb,
    float* __restrict__ agg, float* __restrict__ delta)
{
    __shared__ int   rowS[EPB];
    __shared__ int   colS[EPB];
    __shared__ int   rowD[EPB];     // distinct rows
    __shared__ int   segS[EPB];     // segment id per edge
    __shared__ int   nsegS;
    __shared__ float diffS[EPB][3];
    __shared__ float dist2S[EPB];
    __shared__ float sPart[2][EPB];
    __shared__ float sS[EPB];
    __shared__ float dLDS[EPB * 3];
    // union: h1 (bf16, phase B/C) then aggL (f32, phase E+)
    __shared__ __align__(16) char smemU[EPB * ASTR * 4];
    unsigned short* h1   = (unsigned short*)smemU;
    float*          aggL = (float*)smemU;

    const int t   = threadIdx.x;
    const int w   = t >> 6;
    const int l   = t & 63;
    const int h   = w & 1;        // edge half
    const int qq  = w >> 1;       // feature half
    const int l15 = l & 15;
    const int q8  = l >> 4;       // quad 0..3
    const int e0  = blockIdx.x * EPB;

    // phase A: indices, diff, dist2
    if (t < EPB) {
        int r = sRow[e0 + t];
        int c = sCol[e0 + t];
        rowS[t] = r;
        colS[t] = c;
        float dx = pos[r*3+0] - pos[c*3+0];
        float dy = pos[r*3+1] - pos[c*3+1];
        float dz = pos[r*3+2] - pos[c*3+2];
        diffS[t][0] = dx; diffS[t][1] = dy; diffS[t][2] = dz;
        dist2S[t] = dx*dx + dy*dy + dz*dz;
    }
    __syncthreads();

    // segment computation (rows are sorted ascending within the block)
    if (t == 0) {
        int ns = 0;
        for (int e = 0; e < EPB; ++e) {
            if (e == 0 || rowS[e] != rowS[e-1]) { rowD[ns] = rowS[e]; ++ns; }
            segS[e] = ns - 1;
        }
        nsegS = ns;
    }

    const int m = h * 16 + l15;
    const unsigned short* aRow = xb + (size_t)rowS[m] * FF;
    const unsigned short* aCol = xb + (size_t)colS[m] * FF;

    int ncol[4];
    #pragma unroll
    for (int tt = 0; tt < 4; ++tt) ncol[tt] = qq * 64 + tt * 16 + l15;

    // phase B: GEMM1 (K=256) + dist2 rank-1 + bias + SiLU
    f32x4 acc[4] = {};
    #pragma unroll
    for (int ko = 0; ko < 8; ++ko) {
        const unsigned short* ap = (ko < 4 ? aRow : aCol) + ((ko & 3) * 32 + q8 * 8);
        s16x8 a = *(const s16x8*)ap;
        #pragma unroll
        for (int tt = 0; tt < 4; ++tt) {
            s16x8 b = *(const s16x8*)(ew1T + (size_t)ncol[tt] * 256 + ko * 32 + q8 * 8);
            acc[tt] = __builtin_amdgcn_mfma_f32_16x16x32_bf16(a, b, acc[tt], 0, 0, 0);
        }
    }
    #pragma unroll
    for (int tt = 0; tt < 4; ++tt) {
        int   n    = ncol[tt];
        float w256 = ew1[256 * FF + n];
        float b1   = eb1[n];
        #pragma unroll
        for (int r = 0; r < 4; ++r) {
            int e = h * 16 + q8 * 4 + r;
            float v = acc[tt][r] + dist2S[e] * w256 + b1;
            h1[e * H1S + n] = f2bf(silu_f(v));
        }
    }
    __syncthreads();

    // phase C: GEMM2 (K=128)
    f32x4 acc2[4] = {};
    const unsigned short* hrow = h1 + (h * 16 + l15) * H1S;
    #pragma unroll
    for (int ko = 0; ko < 4; ++ko) {
        s16x8 a = *(const s16x8*)(hrow + ko * 32 + q8 * 8);
        #pragma unroll
        for (int tt = 0; tt < 4; ++tt) {
            s16x8 b = *(const s16x8*)(ew2T + (size_t)ncol[tt] * 128 + ko * 32 + q8 * 8);
            acc2[tt] = __builtin_amdgcn_mfma_f32_16x16x32_bf16(a, b, acc2[tt], 0, 0, 0);
        }
    }
    float msg[4][4];
    #pragma unroll
    for (int tt = 0; tt < 4; ++tt) {
        float b2 = eb2[ncol[tt]];
        #pragma unroll
        for (int r = 0; r < 4; ++r) msg[tt][r] = acc2[tt][r] + b2;
    }

    // phase D: coord scale s[e] = tanh(msg . cw + cb)
    {
        float cwc[4];
        #pragma unroll
        for (int tt = 0; tt < 4; ++tt) cwc[tt] = cw[ncol[tt]];
        #pragma unroll
        for (int r = 0; r < 4; ++r) {
            float p = msg[0][r]*cwc[0] + msg[1][r]*cwc[1] + msg[2][r]*cwc[2] + msg[3][r]*cwc[3];
            #pragma unroll
            for (int off = 1; off < 16; off <<= 1) p += __shfl_xor(p, off);
            if (l15 == 0) sPart[qq][h * 16 + q8 * 4 + r] = p;
        }
    }
    // this barrier also guarantees all h1 reads (phase C) are done before aggL reuse
    __syncthreads();
    if (t < EPB) sS[t] = tanhf(sPart[0][t] + sPart[1][t] + cb[0]);

    // phase E: zero LDS accumulators (only nseg rows)
    const int nseg = nsegS;
    for (int i = t; i < nseg * ASTR; i += 256) aggL[i] = 0.f;
    if (t < EPB * 3) dLDS[t] = 0.f;
    __syncthreads();

    // phase F: LDS segmented accumulation
    #pragma unroll
    for (int r = 0; r < 4; ++r) {
        int e = h * 16 + q8 * 4 + r;
        float* base = aggL + segS[e] * ASTR;
        #pragma unroll
        for (int tt = 0; tt < 4; ++tt)
            atomicAdd(base + ncol[tt], msg[tt][r]);
    }
    if (t < EPB * 3) {
        int e = t / 3, d = t % 3;
        atomicAdd(&dLDS[segS[e] * 3 + d], sS[e] * diffS[e][d]);
    }
    __syncthreads();

    // phase G: one global atomic per (segment, feature)
    for (int s = t >> 7; s < nseg; s += 2) {
        int f = t & 127;
        atomicAdd(&agg[(size_t)rowD[s] * FF + f], aggL[s * ASTR + f]);
    }
    if (t < nseg * 3) {
        int s = t / 3, d = t % 3;
        atomicAdd(&delta[(size_t)rowD[s] * 3 + d], dLDS[s * 3 + d]);
    }
}

// -------------------- node kernel (f32, unchanged) --------------------
constexpr int NPB  = 16;
constexpr int HSTR = 132;

__global__ __launch_bounds__(128) void node_kernel(
    const float* __restrict__ x, const float* __restrict__ pos,
    const float* __restrict__ agg, const float* __restrict__ delta,
    const float* __restrict__ nw1, const float* __restrict__ nb1,
    const float* __restrict__ nw2, const float* __restrict__ nb2,
    const float* __restrict__ gamma, const float* __restrict__ beta,
    float* __restrict__ xout, float* __restrict__ posout)
{
    __shared__ __align__(16) float a[NPB * HSTR];
    __shared__ __align__(16) float h1[NPB * HSTR];
    __shared__ float red[2][NPB][2];

    const int t  = threadIdx.x;
    const int n0 = blockIdx.x * NPB;

    #pragma unroll
    for (int i = 0; i < 4; ++i) {
        int idx = i * 128 + t;
        int e   = idx >> 5;
        int q   = idx & 31;
        *(float4*)&a[e*HSTR + q*4] =
            *(const float4*)&agg[((size_t)(n0 + e)) * FF + q*4];
    }
    __syncthreads();

    float acc[NPB];
    {
        float b = nb1[t];
        #pragma unroll
        for (int e = 0; e < NPB; ++e) acc[e] = b;
    }
    for (int k = 0; k < 128; k += 4) {
        float w0 = nw1[(k+0)*FF + t];
        float w1 = nw1[(k+1)*FF + t];
        float w2 = nw1[(k+2)*FF + t];
        float w3 = nw1[(k+3)*FF + t];
        #pragma unroll
        for (int e = 0; e < NPB; ++e) {
            float4 f = *(const float4*)&a[e*HSTR + k];
            acc[e] = fmaf(f.x, w0, acc[e]);
            acc[e] = fmaf(f.y, w1, acc[e]);
            acc[e] = fmaf(f.z, w2, acc[e]);
            acc[e] = fmaf(f.w, w3, acc[e]);
        }
    }
    #pragma unroll
    for (int e = 0; e < NPB; ++e) h1[e*HSTR + t] = silu_f(acc[e]);
    __syncthreads();

    float upd[NPB];
    {
        float b = nb2[t];
        #pragma unroll
        for (int e = 0; e < NPB; ++e) upd[e] = b;
    }
    for (int k = 0; k < 128; k += 4) {
        float w0 = nw2[(k+0)*FF + t];
        float w1 = nw2[(k+1)*FF + t];
        float w2 = nw2[(k+2)*FF + t];
        float w3 = nw2[(k+3)*FF + t];
        #pragma unroll
        for (int e = 0; e < NPB; ++e) {
            float4 f = *(const float4*)&h1[e*HSTR + k];
            upd[e] = fmaf(f.x, w0, upd[e]);
            upd[e] = fmaf(f.y, w1, upd[e]);
            upd[e] = fmaf(f.z, w2, upd[e]);
            upd[e] = fmaf(f.w, w3, upd[e]);
        }
    }

    #pragma unroll
    for (int e = 0; e < NPB; ++e) {
        float pre = x[((size_t)(n0 + e)) * FF + t] + upd[e];
        float s  = pre;
        float s2 = pre * pre;
        #pragma unroll
        for (int off = 32; off >= 1; off >>= 1) {
            s  += __shfl_down(s,  off);
            s2 += __shfl_down(s2, off);
        }
        if ((t & 63) == 0) { red[t >> 6][e][0] = s; red[t >> 6][e][1] = s2; }
        upd[e] = pre;
    }
    __syncthreads();

    {
        float g = gamma[t], b = beta[t];
        #pragma unroll
        for (int e = 0; e < NPB; ++e) {
            float mean = (red[0][e][0] + red[1][e][0]) * (1.f / FF);
            float m2   = (red[0][e][1] + red[1][e][1]) * (1.f / FF);
            float var  = m2 - mean * mean;
            float xo   = g * (upd[e] - mean) * rsqrtf(var + LN_EPS) + b;
            xout[((size_t)(n0 + e)) * FF + t] = xo;
        }
    }

    if (t < NPB * 3) {
        int e = t / 3, d = t % 3;
        size_t n = (size_t)(n0 + e);
        posout[n*3 + d] = pos[n*3 + d] + delta[n*3 + d];
    }
}

// -------------------- launcher --------------------
extern "C" void kernel_launch(void* const* d_in, const int* in_sizes, int n_in,
                              void* d_out, int out_size, void* d_ws, size_t ws_size,
                              hipStream_t stream) {
    const float* x    = (const float*)d_in[0];
    const float* pos  = (const float*)d_in[1];
    const int*   ei   = (const int*)  d_in[2];
    const float* ew1  = (const float*)d_in[3];
    const float* eb1  = (const float*)d_in[4];
    const float* ew2  = (const float*)d_in[5];
    const float* eb2  = (const float*)d_in[6];
    const float* nw1  = (const float*)d_in[7];
    const float* nb1  = (const float*)d_in[8];
    const float* nw2  = (const float*)d_in[9];
    const float* nb2  = (const float*)d_in[10];
    const float* cw   = (const float*)d_in[11];
    const float* cb   = (const float*)d_in[12];
    const float* gam  = (const float*)d_in[13];
    const float* bet  = (const float*)d_in[14];

    float* out    = (float*)d_out;
    float* xout   = out;
    float* posout = out + (size_t)NN * FF;

    // workspace layout (aligned chunks)
    auto align256 = [](size_t v) { return (v + 255) & ~(size_t)255; };
    char* ws = (char*)d_ws;
    size_t AGG_B   = align256((size_t)NN * FF * 4);   // 25.6 MB
    size_t DELTA_B = align256((size_t)NN * 3 * 4);
    size_t CNT_B   = align256((size_t)NN * 4);
    size_t OFFS_B  = align256((size_t)NN * 4);
    size_t CHNK_B  = align256((size_t)NC * 4 * 2);
    size_t SROW_B  = align256((size_t)EE * 4);

    size_t o = 0;
    float* agg      = (float*)(ws + o);  o += AGG_B;
    float* delta    = (float*)(ws + o);  o += DELTA_B;
    int*   cnt      = (int*)  (ws + o);  o += CNT_B;
    size_t ZERO_B   = o;                                // memset covers agg+delta+cnt
    int*   offs     = (int*)  (ws + o);  o += OFFS_B;
    int*   chunkSum = (int*)  (ws + o);
    int*   chunkOff = chunkSum + NC;     o += CHNK_B;
    int*   sRow     = (int*)  (ws + o);  o += SROW_B;
    int*   sCol     = (int*)  (ws + o);  o += SROW_B;
    unsigned short* xb   = (unsigned short*)(ws + o);  o += (size_t)NN * FF * 2;
    unsigned short* ew1T = (unsigned short*)(ws + o);  o += 128 * 256 * 2;
    unsigned short* ew2T = (unsigned short*)(ws + o);

    hipMemsetAsync(ws, 0, ZERO_B, stream);

    convert_x_kernel<<<(NN * FF / 8) / 256, 256, 0, stream>>>(x, xb);
    transpose_w_kernel<<<(128 * 256 + 128 * 128) / 256, 256, 0, stream>>>(ew1, ew2, ew1T, ew2T);

    hist_kernel<<<EE / 256, 256, 0, stream>>>(ei, cnt);
    chunk_sum_kernel<<<NC, 256, 0, stream>>>(cnt, chunkSum);
    scan_chunks_kernel<<<1, 256, 0, stream>>>(chunkSum, chunkOff);
    scan_kernel<<<NC, 256, 0, stream>>>(cnt, chunkOff, offs);
    scatter_idx_kernel<<<EE / 256, 256, 0, stream>>>(ei, offs, sRow, sCol);

    edge_kernel<<<EE / EPB, 256, 0, stream>>>(
        xb, pos, sRow, sCol, ew1T, ew1, eb1, ew2T, eb2, cw, cb, agg, delta);

    node_kernel<<<NN / NPB, 128, 0, stream>>>(
        x, pos, agg, delta, nw1, nb1, nw2, nb2, gam, bet, xout, posout);
}

// Round 4
// 872.126 us; speedup vs baseline: 1.2602x; 1.2602x over previous
//
#include <hip/hip_runtime.h>
#include <math.h>

#define NN 50000
#define EE 800000
#define FF 128

constexpr float LN_EPS = 1e-5f;
constexpr int NC = (NN + 255) / 256;   // 196 scan chunks

typedef float  f32x4  __attribute__((ext_vector_type(4)));
typedef short  s16x8  __attribute__((ext_vector_type(8)));

__device__ __forceinline__ float silu_f(float v) {
    return v / (1.f + __expf(-v));
}

__device__ __forceinline__ unsigned short f2bf(float f) {
    union { float f; unsigned u; } cv; cv.f = f;
    unsigned u = cv.u;
    u += 0x7fffu + ((u >> 16) & 1u);   // round-to-nearest-even
    return (unsigned short)(u >> 16);
}

__device__ __forceinline__ float bf2f(unsigned short u) {
    union { unsigned u; float f; } cv; cv.u = ((unsigned)u) << 16;
    return cv.f;
}

// -------------------- prep: x -> bf16 --------------------
__global__ __launch_bounds__(256) void convert_x_kernel(
    const float* __restrict__ x, unsigned short* __restrict__ xb)
{
    int i = (blockIdx.x * 256 + threadIdx.x) * 8;
    float4 a = *(const float4*)&x[i];
    float4 b = *(const float4*)&x[i + 4];
    s16x8 o;
    o[0] = (short)f2bf(a.x); o[1] = (short)f2bf(a.y);
    o[2] = (short)f2bf(a.z); o[3] = (short)f2bf(a.w);
    o[4] = (short)f2bf(b.x); o[5] = (short)f2bf(b.y);
    o[6] = (short)f2bf(b.z); o[7] = (short)f2bf(b.w);
    *(s16x8*)&xb[i] = o;
}

// -------------------- prep: transpose weights -> bf16 --------------------
__global__ __launch_bounds__(256) void transpose_w_kernel(
    const float* __restrict__ ew1, const float* __restrict__ ew2,
    unsigned short* __restrict__ ew1T, unsigned short* __restrict__ ew2T)
{
    int o = blockIdx.x * 256 + threadIdx.x;
    if (o < 128 * 256) {
        int n = o >> 8, k = o & 255;
        ew1T[o] = f2bf(ew1[k * FF + n]);
    } else {
        int o2 = o - 128 * 256;
        int n = o2 >> 7, k = o2 & 127;
        ew2T[o2] = f2bf(ew2[k * FF + n]);
    }
}

// -------------------- counting sort by row --------------------
__global__ __launch_bounds__(256) void hist_kernel(
    const int* __restrict__ ei, int* __restrict__ cnt)
{
    int e = blockIdx.x * 256 + threadIdx.x;
    if (e < EE) atomicAdd(&cnt[ei[e]], 1);
}

__global__ __launch_bounds__(256) void chunk_sum_kernel(
    const int* __restrict__ cnt, int* __restrict__ chunkSum)
{
    __shared__ int s[256];
    int t = threadIdx.x;
    int idx = blockIdx.x * 256 + t;
    s[t] = (idx < NN) ? cnt[idx] : 0;
    __syncthreads();
    for (int off = 128; off > 0; off >>= 1) {
        if (t < off) s[t] += s[t + off];
        __syncthreads();
    }
    if (t == 0) chunkSum[blockIdx.x] = s[0];
}

__global__ __launch_bounds__(256) void scan_chunks_kernel(
    const int* __restrict__ chunkSum, int* __restrict__ chunkOff)
{
    __shared__ int s[256];
    int t = threadIdx.x;
    int v = (t < NC) ? chunkSum[t] : 0;
    s[t] = v;
    __syncthreads();
    for (int off = 1; off < 256; off <<= 1) {
        int u = (t >= off) ? s[t - off] : 0;
        __syncthreads();
        s[t] += u;
        __syncthreads();
    }
    if (t < NC) chunkOff[t] = s[t] - v;
}

__global__ __launch_bounds__(256) void scan_kernel(
    const int* __restrict__ cnt, const int* __restrict__ chunkOff,
    int* __restrict__ offs)
{
    __shared__ int s[256];
    int t = threadIdx.x;
    int idx = blockIdx.x * 256 + t;
    int v = (idx < NN) ? cnt[idx] : 0;
    s[t] = v;
    __syncthreads();
    for (int off = 1; off < 256; off <<= 1) {
        int u = (t >= off) ? s[t - off] : 0;
        __syncthreads();
        s[t] += u;
        __syncthreads();
    }
    if (idx < NN) offs[idx] = chunkOff[blockIdx.x] + s[t] - v;
}

__global__ __launch_bounds__(256) void scatter_idx_kernel(
    const int* __restrict__ ei, int* __restrict__ offs,
    int* __restrict__ sRow, int* __restrict__ sCol)
{
    int e = blockIdx.x * 256 + threadIdx.x;
    if (e < EE) {
        int r = ei[e], c = ei[EE + e];
        int p = atomicAdd(&offs[r], 1);
        sRow[p] = r;
        sCol[p] = c;
    }
}

// -------------------- edge kernel --------------------
// 512 threads = 8 waves, 64 edges/block. Wave w: edge quarter h=w&3 (16 edges),
// feature half qq=w>>2 (64 cols as 4 tiles of 16).
constexpr int EPB = 64;
constexpr int H1S = 136;   // bf16 LDS row stride (128 + 8 pad)

__global__ __launch_bounds__(512, 4) void edge_kernel(
    const unsigned short* __restrict__ xb, const float* __restrict__ pos,
    const int* __restrict__ sRow, const int* __restrict__ sCol,
    const unsigned short* __restrict__ ew1T, const float* __restrict__ ew1,
    const float* __restrict__ eb1,
    const unsigned short* __restrict__ ew2T, const float* __restrict__ eb2,
    const float* __restrict__ cw,  const float* __restrict__ cb,
    float* __restrict__ agg, float* __restrict__ delta)
{
    __shared__ int   rowS[EPB];
    __shared__ int   colS[EPB];
    __shared__ int   segS[EPB];
    __shared__ int   rowD[EPB];
    __shared__ int   segStart[EPB];
    __shared__ int   segEnd[EPB];
    __shared__ int   nsegS;
    __shared__ float diffS[EPB][3];
    __shared__ float dist2S[EPB];
    __shared__ float sPart[2][EPB];
    __shared__ float sS[EPB];
    __shared__ __align__(16) unsigned short h1[EPB * H1S];
    __shared__ __align__(16) unsigned short msgL[EPB * H1S];

    const int t   = threadIdx.x;
    const int w   = t >> 6;
    const int l   = t & 63;
    const int h   = w & 3;        // edge quarter
    const int qq  = w >> 2;       // feature half
    const int l15 = l & 15;
    const int q8  = l >> 4;       // quad 0..3
    const int e0  = blockIdx.x * EPB;

    // phase A: indices, diff, dist2, segment structure (wave 0 only)
    if (t < EPB) {
        int r = sRow[e0 + t];
        int c = sCol[e0 + t];
        rowS[t] = r;
        colS[t] = c;
        float dx = pos[r*3+0] - pos[c*3+0];
        float dy = pos[r*3+1] - pos[c*3+1];
        float dz = pos[r*3+2] - pos[c*3+2];
        diffS[t][0] = dx; diffS[t][1] = dy; diffS[t][2] = dz;
        dist2S[t] = dx*dx + dy*dy + dz*dz;

        int rPrev = __shfl_up(r, 1);
        int flag  = (l == 0) || (r != rPrev);
        unsigned long long mask = __ballot(flag);
        int seg = (int)__popcll(mask & ((2ull << l) - 1ull)) - 1;
        segS[t] = seg;
        if (flag) { rowD[seg] = r; segStart[seg] = l; }
        if (flag && l > 0) segEnd[seg - 1] = l;
        if (l == 63) { segEnd[seg] = EPB; nsegS = (int)__popcll(mask); }
    }
    __syncthreads();

    // A-fragment batch preload (8 independent 16B loads)
    const int m = h * 16 + l15;
    const unsigned short* aR = xb + (size_t)rowS[m] * FF;
    const unsigned short* aC = xb + (size_t)colS[m] * FF;
    s16x8 af[8];
    #pragma unroll
    for (int i = 0; i < 4; ++i) {
        af[i]     = *(const s16x8*)(aR + i * 32 + q8 * 8);
        af[4 + i] = *(const s16x8*)(aC + i * 32 + q8 * 8);
    }

    int ncol[4];
    #pragma unroll
    for (int tt = 0; tt < 4; ++tt) ncol[tt] = qq * 64 + tt * 16 + l15;

    // phase B: GEMM1 (K=256) with 1-deep B prefetch
    f32x4 acc[4] = {};
    s16x8 bc[4], bn[4];
    #pragma unroll
    for (int tt = 0; tt < 4; ++tt)
        bc[tt] = *(const s16x8*)(ew1T + (size_t)ncol[tt] * 256 + q8 * 8);
    #pragma unroll
    for (int ko = 0; ko < 8; ++ko) {
        if (ko < 7) {
            #pragma unroll
            for (int tt = 0; tt < 4; ++tt)
                bn[tt] = *(const s16x8*)(ew1T + (size_t)ncol[tt] * 256 + (ko + 1) * 32 + q8 * 8);
        }
        #pragma unroll
        for (int tt = 0; tt < 4; ++tt)
            acc[tt] = __builtin_amdgcn_mfma_f32_16x16x32_bf16(af[ko], bc[tt], acc[tt], 0, 0, 0);
        #pragma unroll
        for (int tt = 0; tt < 4; ++tt) bc[tt] = bn[tt];
    }

    // epilogue: dist2 rank-1 + bias + SiLU -> h1
    #pragma unroll
    for (int tt = 0; tt < 4; ++tt) {
        int   n    = ncol[tt];
        float w256 = ew1[256 * FF + n];
        float b1   = eb1[n];
        #pragma unroll
        for (int r = 0; r < 4; ++r) {
            int e = h * 16 + q8 * 4 + r;
            float v = acc[tt][r] + dist2S[e] * w256 + b1;
            h1[e * H1S + n] = f2bf(silu_f(v));
        }
    }
    __syncthreads();

    // phase C: GEMM2 (K=128), A from LDS (batch), B prefetched
    s16x8 hf[4];
    const unsigned short* hrow = h1 + (h * 16 + l15) * H1S;
    #pragma unroll
    for (int ko = 0; ko < 4; ++ko)
        hf[ko] = *(const s16x8*)(hrow + ko * 32 + q8 * 8);

    f32x4 acc2[4] = {};
    #pragma unroll
    for (int tt = 0; tt < 4; ++tt)
        bc[tt] = *(const s16x8*)(ew2T + (size_t)ncol[tt] * 128 + q8 * 8);
    #pragma unroll
    for (int ko = 0; ko < 4; ++ko) {
        if (ko < 3) {
            #pragma unroll
            for (int tt = 0; tt < 4; ++tt)
                bn[tt] = *(const s16x8*)(ew2T + (size_t)ncol[tt] * 128 + (ko + 1) * 32 + q8 * 8);
        }
        #pragma unroll
        for (int tt = 0; tt < 4; ++tt)
            acc2[tt] = __builtin_amdgcn_mfma_f32_16x16x32_bf16(hf[ko], bc[tt], acc2[tt], 0, 0, 0);
        #pragma unroll
        for (int tt = 0; tt < 4; ++tt) bc[tt] = bn[tt];
    }

    float msg[4][4];
    #pragma unroll
    for (int tt = 0; tt < 4; ++tt) {
        float b2 = eb2[ncol[tt]];
        #pragma unroll
        for (int r = 0; r < 4; ++r) msg[tt][r] = acc2[tt][r] + b2;
    }

    // phase D: coord-scale partial reduction + msg -> LDS
    {
        float cwc[4];
        #pragma unroll
        for (int tt = 0; tt < 4; ++tt) cwc[tt] = cw[ncol[tt]];
        #pragma unroll
        for (int r = 0; r < 4; ++r) {
            float p = msg[0][r]*cwc[0] + msg[1][r]*cwc[1] + msg[2][r]*cwc[2] + msg[3][r]*cwc[3];
            #pragma unroll
            for (int off = 1; off < 16; off <<= 1) p += __shfl_xor(p, off);
            if (l15 == 0) sPart[qq][h * 16 + q8 * 4 + r] = p;
        }
    }
    #pragma unroll
    for (int tt = 0; tt < 4; ++tt) {
        #pragma unroll
        for (int r = 0; r < 4; ++r) {
            int e = h * 16 + q8 * 4 + r;
            msgL[e * H1S + ncol[tt]] = f2bf(msg[tt][r]);
        }
    }
    __syncthreads();

    if (t < EPB) sS[t] = tanhf(sPart[0][t] + sPart[1][t] + cb[0]);
    __syncthreads();

    // phase E: segmented sums + one global atomic per (segment, feature)
    const int nseg = nsegS;
    {
        int f = t & 127;
        for (int s = t >> 7; s < nseg; s += 4) {
            float sum = 0.f;
            int eEnd = segEnd[s];
            for (int e = segStart[s]; e < eEnd; ++e)
                sum += bf2f(msgL[e * H1S + f]);
            atomicAdd(&agg[(size_t)rowD[s] * FF + f], sum);
        }
    }
    if (t < nseg * 3) {
        int s = t / 3, d = t % 3;
        float sum = 0.f;
        int eEnd = segEnd[s];
        for (int e = segStart[s]; e < eEnd; ++e)
            sum += sS[e] * diffS[e][d];
        atomicAdd(&delta[(size_t)rowD[s] * 3 + d], sum);
    }
}

// -------------------- node kernel (f32, unchanged) --------------------
constexpr int NPB  = 16;
constexpr int HSTR = 132;

__global__ __launch_bounds__(128) void node_kernel(
    const float* __restrict__ x, const float* __restrict__ pos,
    const float* __restrict__ agg, const float* __restrict__ delta,
    const float* __restrict__ nw1, const float* __restrict__ nb1,
    const float* __restrict__ nw2, const float* __restrict__ nb2,
    const float* __restrict__ gamma, const float* __restrict__ beta,
    float* __restrict__ xout, float* __restrict__ posout)
{
    __shared__ __align__(16) float a[NPB * HSTR];
    __shared__ __align__(16) float h1[NPB * HSTR];
    __shared__ float red[2][NPB][2];

    const int t  = threadIdx.x;
    const int n0 = blockIdx.x * NPB;

    #pragma unroll
    for (int i = 0; i < 4; ++i) {
        int idx = i * 128 + t;
        int e   = idx >> 5;
        int q   = idx & 31;
        *(float4*)&a[e*HSTR + q*4] =
            *(const float4*)&agg[((size_t)(n0 + e)) * FF + q*4];
    }
    __syncthreads();

    float acc[NPB];
    {
        float b = nb1[t];
        #pragma unroll
        for (int e = 0; e < NPB; ++e) acc[e] = b;
    }
    for (int k = 0; k < 128; k += 4) {
        float w0 = nw1[(k+0)*FF + t];
        float w1 = nw1[(k+1)*FF + t];
        float w2 = nw1[(k+2)*FF + t];
        float w3 = nw1[(k+3)*FF + t];
        #pragma unroll
        for (int e = 0; e < NPB; ++e) {
            float4 f = *(const float4*)&a[e*HSTR + k];
            acc[e] = fmaf(f.x, w0, acc[e]);
            acc[e] = fmaf(f.y, w1, acc[e]);
            acc[e] = fmaf(f.z, w2, acc[e]);
            acc[e] = fmaf(f.w, w3, acc[e]);
        }
    }
    #pragma unroll
    for (int e = 0; e < NPB; ++e) h1[e*HSTR + t] = silu_f(acc[e]);
    __syncthreads();

    float upd[NPB];
    {
        float b = nb2[t];
        #pragma unroll
        for (int e = 0; e < NPB; ++e) upd[e] = b;
    }
    for (int k = 0; k < 128; k += 4) {
        float w0 = nw2[(k+0)*FF + t];
        float w1 = nw2[(k+1)*FF + t];
        float w2 = nw2[(k+2)*FF + t];
        float w3 = nw2[(k+3)*FF + t];
        #pragma unroll
        for (int e = 0; e < NPB; ++e) {
            float4 f = *(const float4*)&h1[e*HSTR + k];
            upd[e] = fmaf(f.x, w0, upd[e]);
            upd[e] = fmaf(f.y, w1, upd[e]);
            upd[e] = fmaf(f.z, w2, upd[e]);
            upd[e] = fmaf(f.w, w3, upd[e]);
        }
    }

    #pragma unroll
    for (int e = 0; e < NPB; ++e) {
        float pre = x[((size_t)(n0 + e)) * FF + t] + upd[e];
        float s  = pre;
        float s2 = pre * pre;
        #pragma unroll
        for (int off = 32; off >= 1; off >>= 1) {
            s  += __shfl_down(s,  off);
            s2 += __shfl_down(s2, off);
        }
        if ((t & 63) == 0) { red[t >> 6][e][0] = s; red[t >> 6][e][1] = s2; }
        upd[e] = pre;
    }
    __syncthreads();

    {
        float g = gamma[t], b = beta[t];
        #pragma unroll
        for (int e = 0; e < NPB; ++e) {
            float mean = (red[0][e][0] + red[1][e][0]) * (1.f / FF);
            float m2   = (red[0][e][1] + red[1][e][1]) * (1.f / FF);
            float var  = m2 - mean * mean;
            float xo   = g * (upd[e] - mean) * rsqrtf(var + LN_EPS) + b;
            xout[((size_t)(n0 + e)) * FF + t] = xo;
        }
    }

    if (t < NPB * 3) {
        int e = t / 3, d = t % 3;
        size_t n = (size_t)(n0 + e);
        posout[n*3 + d] = pos[n*3 + d] + delta[n*3 + d];
    }
}

// -------------------- launcher --------------------
extern "C" void kernel_launch(void* const* d_in, const int* in_sizes, int n_in,
                              void* d_out, int out_size, void* d_ws, size_t ws_size,
                              hipStream_t stream) {
    const float* x    = (const float*)d_in[0];
    const float* pos  = (const float*)d_in[1];
    const int*   ei   = (const int*)  d_in[2];
    const float* ew1  = (const float*)d_in[3];
    const float* eb1  = (const float*)d_in[4];
    const float* ew2  = (const float*)d_in[5];
    const float* eb2  = (const float*)d_in[6];
    const float* nw1  = (const float*)d_in[7];
    const float* nb1  = (const float*)d_in[8];
    const float* nw2  = (const float*)d_in[9];
    const float* nb2  = (const float*)d_in[10];
    const float* cw   = (const float*)d_in[11];
    const float* cb   = (const float*)d_in[12];
    const float* gam  = (const float*)d_in[13];
    const float* bet  = (const float*)d_in[14];

    float* out    = (float*)d_out;
    float* xout   = out;
    float* posout = out + (size_t)NN * FF;

    auto align256 = [](size_t v) { return (v + 255) & ~(size_t)255; };
    char* ws = (char*)d_ws;
    size_t AGG_B   = align256((size_t)NN * FF * 4);   // 25.6 MB
    size_t DELTA_B = align256((size_t)NN * 3 * 4);
    size_t CNT_B   = align256((size_t)NN * 4);
    size_t OFFS_B  = align256((size_t)NN * 4);
    size_t CHNK_B  = align256((size_t)NC * 4 * 2);
    size_t SROW_B  = align256((size_t)EE * 4);

    size_t o = 0;
    float* agg      = (float*)(ws + o);  o += AGG_B;
    float* delta    = (float*)(ws + o);  o += DELTA_B;
    int*   cnt      = (int*)  (ws + o);  o += CNT_B;
    size_t ZERO_B   = o;                                // memset covers agg+delta+cnt
    int*   offs     = (int*)  (ws + o);  o += OFFS_B;
    int*   chunkSum = (int*)  (ws + o);
    int*   chunkOff = chunkSum + NC;     o += CHNK_B;
    int*   sRow     = (int*)  (ws + o);  o += SROW_B;
    int*   sCol     = (int*)  (ws + o);  o += SROW_B;
    unsigned short* xb   = (unsigned short*)(ws + o);  o += (size_t)NN * FF * 2;
    unsigned short* ew1T = (unsigned short*)(ws + o);  o += 128 * 256 * 2;
    unsigned short* ew2T = (unsigned short*)(ws + o);

    hipMemsetAsync(ws, 0, ZERO_B, stream);

    convert_x_kernel<<<(NN * FF / 8) / 256, 256, 0, stream>>>(x, xb);
    transpose_w_kernel<<<(128 * 256 + 128 * 128) / 256, 256, 0, stream>>>(ew1, ew2, ew1T, ew2T);

    hist_kernel<<<EE / 256, 256, 0, stream>>>(ei, cnt);
    chunk_sum_kernel<<<NC, 256, 0, stream>>>(cnt, chunkSum);
    scan_chunks_kernel<<<1, 256, 0, stream>>>(chunkSum, chunkOff);
    scan_kernel<<<NC, 256, 0, stream>>>(cnt, chunkOff, offs);
    scatter_idx_kernel<<<EE / 256, 256, 0, stream>>>(ei, offs, sRow, sCol);

    edge_kernel<<<EE / EPB, 512, 0, stream>>>(
        xb, pos, sRow, sCol, ew1T, ew1, eb1, ew2T, eb2, cw, cb, agg, delta);

    node_kernel<<<NN / NPB, 128, 0, stream>>>(
        x, pos, agg, delta, nw1, nb1, nw2, nb2, gam, bet, xout, posout);
}

// Round 5
// 724.012 us; speedup vs baseline: 1.5180x; 1.2046x over previous
//
#include <hip/hip_runtime.h>
#include <math.h>

#define NN 50000
#define EE 800000
#define FF 128

constexpr float LN_EPS = 1e-5f;
constexpr int NC = (NN + 255) / 256;   // 196 scan chunks

typedef float  f32x4  __attribute__((ext_vector_type(4)));
typedef short  s16x8  __attribute__((ext_vector_type(8)));

__device__ __forceinline__ float silu_f(float v) {
    return v / (1.f + __expf(-v));
}

__device__ __forceinline__ unsigned short f2bf(float f) {
    union { float f; unsigned u; } cv; cv.f = f;
    unsigned u = cv.u;
    u += 0x7fffu + ((u >> 16) & 1u);   // round-to-nearest-even
    return (unsigned short)(u >> 16);
}

__device__ __forceinline__ float bf2f(unsigned short u) {
    union { unsigned u; float f; } cv; cv.u = ((unsigned)u) << 16;
    return cv.f;
}

// -------------------- prep: x -> bf16 --------------------
__global__ __launch_bounds__(256) void convert_x_kernel(
    const float* __restrict__ x, unsigned short* __restrict__ xb)
{
    int i = (blockIdx.x * 256 + threadIdx.x) * 8;
    float4 a = *(const float4*)&x[i];
    float4 b = *(const float4*)&x[i + 4];
    s16x8 o;
    o[0] = (short)f2bf(a.x); o[1] = (short)f2bf(a.y);
    o[2] = (short)f2bf(a.z); o[3] = (short)f2bf(a.w);
    o[4] = (short)f2bf(b.x); o[5] = (short)f2bf(b.y);
    o[6] = (short)f2bf(b.z); o[7] = (short)f2bf(b.w);
    *(s16x8*)&xb[i] = o;
}

// -------------------- prep: transpose weights -> bf16 --------------------
__global__ __launch_bounds__(256) void transpose_w_kernel(
    const float* __restrict__ ew1, const float* __restrict__ ew2,
    unsigned short* __restrict__ ew1T, unsigned short* __restrict__ ew2T)
{
    int o = blockIdx.x * 256 + threadIdx.x;
    if (o < 128 * 256) {
        int n = o >> 8, k = o & 255;
        ew1T[o] = f2bf(ew1[k * FF + n]);
    } else {
        int o2 = o - 128 * 256;
        int n = o2 >> 7, k = o2 & 127;
        ew2T[o2] = f2bf(ew2[k * FF + n]);
    }
}

// -------------------- counting sort by row --------------------
__global__ __launch_bounds__(256) void hist_kernel(
    const int* __restrict__ ei, int* __restrict__ cnt)
{
    int e = blockIdx.x * 256 + threadIdx.x;
    if (e < EE) atomicAdd(&cnt[ei[e]], 1);
}

__global__ __launch_bounds__(256) void chunk_sum_kernel(
    const int* __restrict__ cnt, int* __restrict__ chunkSum)
{
    __shared__ int s[256];
    int t = threadIdx.x;
    int idx = blockIdx.x * 256 + t;
    s[t] = (idx < NN) ? cnt[idx] : 0;
    __syncthreads();
    for (int off = 128; off > 0; off >>= 1) {
        if (t < off) s[t] += s[t + off];
        __syncthreads();
    }
    if (t == 0) chunkSum[blockIdx.x] = s[0];
}

__global__ __launch_bounds__(256) void scan_chunks_kernel(
    const int* __restrict__ chunkSum, int* __restrict__ chunkOff)
{
    __shared__ int s[256];
    int t = threadIdx.x;
    int v = (t < NC) ? chunkSum[t] : 0;
    s[t] = v;
    __syncthreads();
    for (int off = 1; off < 256; off <<= 1) {
        int u = (t >= off) ? s[t - off] : 0;
        __syncthreads();
        s[t] += u;
        __syncthreads();
    }
    if (t < NC) chunkOff[t] = s[t] - v;
}

__global__ __launch_bounds__(256) void scan_kernel(
    const int* __restrict__ cnt, const int* __restrict__ chunkOff,
    int* __restrict__ offs)
{
    __shared__ int s[256];
    int t = threadIdx.x;
    int idx = blockIdx.x * 256 + t;
    int v = (idx < NN) ? cnt[idx] : 0;
    s[t] = v;
    __syncthreads();
    for (int off = 1; off < 256; off <<= 1) {
        int u = (t >= off) ? s[t - off] : 0;
        __syncthreads();
        s[t] += u;
        __syncthreads();
    }
    if (idx < NN) offs[idx] = chunkOff[blockIdx.x] + s[t] - v;
}

__global__ __launch_bounds__(256) void scatter_idx_kernel(
    const int* __restrict__ ei, int* __restrict__ offs,
    int* __restrict__ sRow, int* __restrict__ sCol)
{
    int e = blockIdx.x * 256 + threadIdx.x;
    if (e < EE) {
        int r = ei[e], c = ei[EE + e];
        int p = atomicAdd(&offs[r], 1);
        sRow[p] = r;
        sCol[p] = c;
    }
}

// -------------------- edge kernel: persistent weights + LDS-staged A ------
// 512 threads = 8 waves. Wave w owns output columns [w*16, w*16+16).
// Grid-stride over 64-edge tiles. B-fragments live in registers all kernel.
constexpr int EPB   = 64;
constexpr int NTILE = EE / EPB;    // 12500
constexpr int XAS   = 264;         // xa stride (elems): 256 + 8 pad
constexpr int H1S   = 132;         // h1 / msgL stride (elems): 128 + 4 pad

__global__ __launch_bounds__(512, 4) void edge_kernel(
    const unsigned short* __restrict__ xb, const float* __restrict__ pos,
    const int* __restrict__ sRow, const int* __restrict__ sCol,
    const unsigned short* __restrict__ ew1T, const float* __restrict__ ew1,
    const float* __restrict__ eb1,
    const unsigned short* __restrict__ ew2T, const float* __restrict__ eb2,
    const float* __restrict__ cw,  const float* __restrict__ cb,
    float* __restrict__ agg, float* __restrict__ delta)
{
    __shared__ int   rowS[EPB];
    __shared__ int   colS[EPB];
    __shared__ int   rowD[EPB];
    __shared__ int   segStart[EPB];
    __shared__ int   segEnd[EPB];
    __shared__ int   nsegS;
    __shared__ float diffS[EPB][3];
    __shared__ float dist2S[EPB];
    __shared__ float sPart[8][EPB];
    __shared__ float sS[EPB];
    // xa: 64 x 264 bf16 = 33792 B. Reused: h1 = elems [0, 8448), msgL = [8448, 16896).
    __shared__ __align__(16) unsigned short xa[EPB * XAS];
    unsigned short* h1   = xa;
    unsigned short* msgL = xa + EPB * H1S;   // 64*132 = 8448

    const int t   = threadIdx.x;
    const int w   = t >> 6;
    const int l   = t & 63;
    const int l15 = l & 15;
    const int q8  = l >> 4;          // 0..3
    const int n   = w * 16 + l15;    // this lane's output column

    // ---- persistent per-lane state (lives in registers across all tiles) ----
    s16x8 B1[8], B2[4];
    #pragma unroll
    for (int ko = 0; ko < 8; ++ko)
        B1[ko] = *(const s16x8*)(ew1T + (size_t)n * 256 + ko * 32 + q8 * 8);
    #pragma unroll
    for (int ko = 0; ko < 4; ++ko)
        B2[ko] = *(const s16x8*)(ew2T + (size_t)n * 128 + ko * 32 + q8 * 8);
    const float w256 = ew1[256 * FF + n];
    const float b1   = eb1[n];
    const float b2   = eb2[n];
    const float cwc  = cw[n];
    const float cb0  = cb[0];

    for (int tile = blockIdx.x; tile < NTILE; tile += gridDim.x) {
        const int e0 = tile * EPB;

        // phase A: meta (wave 0)
        if (t < EPB) {
            int r = sRow[e0 + t];
            int c = sCol[e0 + t];
            rowS[t] = r;
            colS[t] = c;
            float dx = pos[r*3+0] - pos[c*3+0];
            float dy = pos[r*3+1] - pos[c*3+1];
            float dz = pos[r*3+2] - pos[c*3+2];
            diffS[t][0] = dx; diffS[t][1] = dy; diffS[t][2] = dz;
            dist2S[t] = dx*dx + dy*dy + dz*dz;

            int rPrev = __shfl_up(r, 1);
            int flag  = (l == 0) || (r != rPrev);
            unsigned long long mask = __ballot(flag);
            int seg = (int)__popcll(mask & ((2ull << l) - 1ull)) - 1;
            if (flag) { rowD[seg] = r; segStart[seg] = l; }
            if (flag && l > 0) segEnd[seg - 1] = l;
            if (l == 63) { segEnd[seg] = EPB; nsegS = (int)__popcll(mask); }
        }
        __syncthreads();

        // phase S: stage A tile into LDS (64 edges x 256 k, bf16)
        #pragma unroll
        for (int i = 0; i < 4; ++i) {
            int idx = i * 512 + t;          // 0..2047
            int e   = idx >> 5;             // edge
            int q   = idx & 31;             // 8-elem chunk: 0..15 row, 16..31 col
            int node = (q < 16) ? rowS[e] : colS[e];
            s16x8 v = *(const s16x8*)(xb + (size_t)node * FF + (q & 15) * 8);
            *(s16x8*)(xa + e * XAS + q * 8) = v;
        }
        __syncthreads();

        // phase B: GEMM1 (64x16 per wave, K=256), A from LDS, B from registers
        f32x4 acc[4] = {};
        #pragma unroll
        for (int mt = 0; mt < 4; ++mt) {
            const unsigned short* ar = xa + (mt * 16 + l15) * XAS + q8 * 8;
            #pragma unroll
            for (int ko = 0; ko < 8; ++ko) {
                s16x8 a = *(const s16x8*)(ar + ko * 32);
                acc[mt] = __builtin_amdgcn_mfma_f32_16x16x32_bf16(a, B1[ko], acc[mt], 0, 0, 0);
            }
        }
        __syncthreads();   // all xa reads done before h1 overwrites it

        // epilogue: dist2 rank-1 + bias + SiLU -> h1
        #pragma unroll
        for (int mt = 0; mt < 4; ++mt) {
            #pragma unroll
            for (int r = 0; r < 4; ++r) {
                int e = mt * 16 + q8 * 4 + r;
                float v = acc[mt][r] + dist2S[e] * w256 + b1;
                h1[e * H1S + n] = f2bf(silu_f(v));
            }
        }
        __syncthreads();

        // phase C: GEMM2 (K=128), A from LDS, B from registers
        f32x4 acc2[4] = {};
        #pragma unroll
        for (int mt = 0; mt < 4; ++mt) {
            const unsigned short* hr = h1 + (mt * 16 + l15) * H1S + q8 * 8;
            #pragma unroll
            for (int ko = 0; ko < 4; ++ko) {
                s16x8 a = *(const s16x8*)(hr + ko * 32);
                acc2[mt] = __builtin_amdgcn_mfma_f32_16x16x32_bf16(a, B2[ko], acc2[mt], 0, 0, 0);
            }
        }

        // phase D: coord-scale partials (this wave's 16-col slice)
        #pragma unroll
        for (int mt = 0; mt < 4; ++mt) {
            #pragma unroll
            for (int r = 0; r < 4; ++r) {
                float p = (acc2[mt][r] + b2) * cwc;
                p += __shfl_xor(p, 1);
                p += __shfl_xor(p, 2);
                p += __shfl_xor(p, 4);
                p += __shfl_xor(p, 8);
                if (l15 == 0) sPart[w][mt * 16 + q8 * 4 + r] = p;
            }
        }
        __syncthreads();   // h1 reads + sPart writes done

        // msg -> msgL (region disjoint from h1), tanh combine
        #pragma unroll
        for (int mt = 0; mt < 4; ++mt) {
            #pragma unroll
            for (int r = 0; r < 4; ++r) {
                int e = mt * 16 + q8 * 4 + r;
                msgL[e * H1S + n] = f2bf(acc2[mt][r] + b2);
            }
        }
        if (t < EPB) {
            float p = 0.f;
            #pragma unroll
            for (int ww = 0; ww < 8; ++ww) p += sPart[ww][t];
            sS[t] = tanhf(p + cb0);
        }
        __syncthreads();

        // phase E: segmented sums + one global atomic per (segment, feature)
        const int nseg = nsegS;
        {
            int f = t & 127;
            for (int s = t >> 7; s < nseg; s += 4) {
                float sum = 0.f;
                int eEnd = segEnd[s];
                for (int e = segStart[s]; e < eEnd; ++e)
                    sum += bf2f(msgL[e * H1S + f]);
                atomicAdd(&agg[(size_t)rowD[s] * FF + f], sum);
            }
        }
        if (t < nseg * 3) {
            int s = t / 3, d = t % 3;
            float sum = 0.f;
            int eEnd = segEnd[s];
            for (int e = segStart[s]; e < eEnd; ++e)
                sum += sS[e] * diffS[e][d];
            atomicAdd(&delta[(size_t)rowD[s] * 3 + d], sum);
        }
        __syncthreads();   // protect LDS reuse before next tile's meta/staging
    }
}

// -------------------- node kernel (f32, unchanged) --------------------
constexpr int NPB  = 16;
constexpr int HSTR = 132;

__global__ __launch_bounds__(128) void node_kernel(
    const float* __restrict__ x, const float* __restrict__ pos,
    const float* __restrict__ agg, const float* __restrict__ delta,
    const float* __restrict__ nw1, const float* __restrict__ nb1,
    const float* __restrict__ nw2, const float* __restrict__ nb2,
    const float* __restrict__ gamma, const float* __restrict__ beta,
    float* __restrict__ xout, float* __restrict__ posout)
{
    __shared__ __align__(16) float a[NPB * HSTR];
    __shared__ __align__(16) float h1[NPB * HSTR];
    __shared__ float red[2][NPB][2];

    const int t  = threadIdx.x;
    const int n0 = blockIdx.x * NPB;

    #pragma unroll
    for (int i = 0; i < 4; ++i) {
        int idx = i * 128 + t;
        int e   = idx >> 5;
        int q   = idx & 31;
        *(float4*)&a[e*HSTR + q*4] =
            *(const float4*)&agg[((size_t)(n0 + e)) * FF + q*4];
    }
    __syncthreads();

    float acc[NPB];
    {
        float b = nb1[t];
        #pragma unroll
        for (int e = 0; e < NPB; ++e) acc[e] = b;
    }
    for (int k = 0; k < 128; k += 4) {
        float w0 = nw1[(k+0)*FF + t];
        float w1 = nw1[(k+1)*FF + t];
        float w2 = nw1[(k+2)*FF + t];
        float w3 = nw1[(k+3)*FF + t];
        #pragma unroll
        for (int e = 0; e < NPB; ++e) {
            float4 f = *(const float4*)&a[e*HSTR + k];
            acc[e] = fmaf(f.x, w0, acc[e]);
            acc[e] = fmaf(f.y, w1, acc[e]);
            acc[e] = fmaf(f.z, w2, acc[e]);
            acc[e] = fmaf(f.w, w3, acc[e]);
        }
    }
    #pragma unroll
    for (int e = 0; e < NPB; ++e) h1[e*HSTR + t] = silu_f(acc[e]);
    __syncthreads();

    float upd[NPB];
    {
        float b = nb2[t];
        #pragma unroll
        for (int e = 0; e < NPB; ++e) upd[e] = b;
    }
    for (int k = 0; k < 128; k += 4) {
        float w0 = nw2[(k+0)*FF + t];
        float w1 = nw2[(k+1)*FF + t];
        float w2 = nw2[(k+2)*FF + t];
        float w3 = nw2[(k+3)*FF + t];
        #pragma unroll
        for (int e = 0; e < NPB; ++e) {
            float4 f = *(const float4*)&h1[e*HSTR + k];
            upd[e] = fmaf(f.x, w0, upd[e]);
            upd[e] = fmaf(f.y, w1, upd[e]);
            upd[e] = fmaf(f.z, w2, upd[e]);
            upd[e] = fmaf(f.w, w3, upd[e]);
        }
    }

    #pragma unroll
    for (int e = 0; e < NPB; ++e) {
        float pre = x[((size_t)(n0 + e)) * FF + t] + upd[e];
        float s  = pre;
        float s2 = pre * pre;
        #pragma unroll
        for (int off = 32; off >= 1; off >>= 1) {
            s  += __shfl_down(s,  off);
            s2 += __shfl_down(s2, off);
        }
        if ((t & 63) == 0) { red[t >> 6][e][0] = s; red[t >> 6][e][1] = s2; }
        upd[e] = pre;
    }
    __syncthreads();

    {
        float g = gamma[t], b = beta[t];
        #pragma unroll
        for (int e = 0; e < NPB; ++e) {
            float mean = (red[0][e][0] + red[1][e][0]) * (1.f / FF);
            float m2   = (red[0][e][1] + red[1][e][1]) * (1.f / FF);
            float var  = m2 - mean * mean;
            float xo   = g * (upd[e] - mean) * rsqrtf(var + LN_EPS) + b;
            xout[((size_t)(n0 + e)) * FF + t] = xo;
        }
    }

    if (t < NPB * 3) {
        int e = t / 3, d = t % 3;
        size_t n = (size_t)(n0 + e);
        posout[n*3 + d] = pos[n*3 + d] + delta[n*3 + d];
    }
}

// -------------------- launcher --------------------
extern "C" void kernel_launch(void* const* d_in, const int* in_sizes, int n_in,
                              void* d_out, int out_size, void* d_ws, size_t ws_size,
                              hipStream_t stream) {
    const float* x    = (const float*)d_in[0];
    const float* pos  = (const float*)d_in[1];
    const int*   ei   = (const int*)  d_in[2];
    const float* ew1  = (const float*)d_in[3];
    const float* eb1  = (const float*)d_in[4];
    const float* ew2  = (const float*)d_in[5];
    const float* eb2  = (const float*)d_in[6];
    const float* nw1  = (const float*)d_in[7];
    const float* nb1  = (const float*)d_in[8];
    const float* nw2  = (const float*)d_in[9];
    const float* nb2  = (const float*)d_in[10];
    const float* cw   = (const float*)d_in[11];
    const float* cb   = (const float*)d_in[12];
    const float* gam  = (const float*)d_in[13];
    const float* bet  = (const float*)d_in[14];

    float* out    = (float*)d_out;
    float* xout   = out;
    float* posout = out + (size_t)NN * FF;

    auto align256 = [](size_t v) { return (v + 255) & ~(size_t)255; };
    char* ws = (char*)d_ws;
    size_t AGG_B   = align256((size_t)NN * FF * 4);   // 25.6 MB
    size_t DELTA_B = align256((size_t)NN * 3 * 4);
    size_t CNT_B   = align256((size_t)NN * 4);
    size_t OFFS_B  = align256((size_t)NN * 4);
    size_t CHNK_B  = align256((size_t)NC * 4 * 2);
    size_t SROW_B  = align256((size_t)EE * 4);

    size_t o = 0;
    float* agg      = (float*)(ws + o);  o += AGG_B;
    float* delta    = (float*)(ws + o);  o += DELTA_B;
    int*   cnt      = (int*)  (ws + o);  o += CNT_B;
    size_t ZERO_B   = o;                                // memset covers agg+delta+cnt
    int*   offs     = (int*)  (ws + o);  o += OFFS_B;
    int*   chunkSum = (int*)  (ws + o);
    int*   chunkOff = chunkSum + NC;     o += CHNK_B;
    int*   sRow     = (int*)  (ws + o);  o += SROW_B;
    int*   sCol     = (int*)  (ws + o);  o += SROW_B;
    unsigned short* xb   = (unsigned short*)(ws + o);  o += (size_t)NN * FF * 2;
    unsigned short* ew1T = (unsigned short*)(ws + o);  o += 128 * 256 * 2;
    unsigned short* ew2T = (unsigned short*)(ws + o);

    hipMemsetAsync(ws, 0, ZERO_B, stream);

    convert_x_kernel<<<(NN * FF / 8) / 256, 256, 0, stream>>>(x, xb);
    transpose_w_kernel<<<(128 * 256 + 128 * 128) / 256, 256, 0, stream>>>(ew1, ew2, ew1T, ew2T);

    hist_kernel<<<EE / 256, 256, 0, stream>>>(ei, cnt);
    chunk_sum_kernel<<<NC, 256, 0, stream>>>(cnt, chunkSum);
    scan_chunks_kernel<<<1, 256, 0, stream>>>(chunkSum, chunkOff);
    scan_kernel<<<NC, 256, 0, stream>>>(cnt, chunkOff, offs);
    scatter_idx_kernel<<<EE / 256, 256, 0, stream>>>(ei, offs, sRow, sCol);

    edge_kernel<<<1024, 512, 0, stream>>>(
        xb, pos, sRow, sCol, ew1T, ew1, eb1, ew2T, eb2, cw, cb, agg, delta);

    node_kernel<<<NN / NPB, 128, 0, stream>>>(
        x, pos, agg, delta, nw1, nb1, nw2, nb2, gam, bet, xout, posout);
}